// Round 10
// baseline (497.561 us; speedup 1.0000x reference)
//
#include <hip/hip_runtime.h>

#define NN 50000
#define NE 800000
#define HD 64
#define NL 2
#define NT_E (NE / 16)   // 50000 edge tiles
#define NT_N (NN / 16)   // 3125 node tiles
#define NCH 196          // scan chunks: 196*256 = 50176 >= NN+1

typedef __attribute__((ext_vector_type(4))) float f32x4;
typedef __attribute__((ext_vector_type(8))) short s16x8;

// ---- d_ws layout (float element offsets) ----
#define FLAG_OFF 0
#define WB_OFF   16
#define EMB_O 0
#define EW1_O 6400
#define EB1_O 22912
#define EW2_O 23040
#define EB2_O 31232
#define HW1_O 31360
#define HB1_O 47744
#define HW2_O 47872
#define HB2_O 56064
#define XW1_O 56192
#define XB1_O 64384
#define XW2_O 64512
#define XB2_O 64640
#define X_OFF    (WB_OFF + 64656)              // fp32 x, padded [NN][4]
#define MAGG_OFF (X_OFF + NN * 4)
#define XAGG_OFF (MAGG_OFF + NN * HD)
#define HBF_OFF  (XAGG_OFF + NN * 3)           // ushort[NN*64]
#define CNT_OFF  (HBF_OFF + NN * 32)
#define CSUM_OFF (CNT_OFF + NCH * 256)
#define INCL_OFF (CSUM_OFF + 256)
#define PAIR_OFF (INCL_OFF + NCH * 256)        // int2[NE]

#define ROWP 72

__device__ __forceinline__ float bf2f(unsigned short u) {
    return __uint_as_float(((unsigned int)u) << 16);
}
__device__ __forceinline__ unsigned short f2bf(float f) {      // RNE
    unsigned int i = __float_as_uint(f);
    i += 0x7fffu + ((i >> 16) & 1u);
    return (unsigned short)(i >> 16);
}
__device__ __forceinline__ unsigned short f2bf_t(float f) {    // trunc (GEMM temps)
    return (unsigned short)(__float_as_uint(f) >> 16);
}
__device__ __forceinline__ float silu(float v) {               // no div sequence
    const float e = __expf(-v);
    return v * __builtin_amdgcn_rcpf(1.0f + e);
}
__device__ __forceinline__ float ldf(const void* p, int i, int bf) {
    return bf ? bf2f(((const unsigned short*)p)[i]) : ((const float*)p)[i];
}
// per-wave bf16-vs-fp32 input detection (all waves agree; no global dep)
__device__ __forceinline__ int detect_bf(const void* pos) {
    const int lane = threadIdx.x & 63;
    const float v = bf2f(((const unsigned short*)pos)[2 * lane]);
    const float a = fabsf(v);
    const unsigned long long m = __ballot(a >= 1e-6f && a <= 1e6f);
    return (__popcll(m) >= 32) ? 1 : 0;
}

// -------------------------------------------------------------- prep --------
// Fused: detect + convert(x, weights) + init_h + hist. cnt must be pre-zeroed.
__global__ __launch_bounds__(256) void prep_kernel(
    const int* __restrict__ an, const void* pos, const int* __restrict__ ei,
    const void* emb,
    const void* ew1, const void* eb1, const void* ew2, const void* eb2,
    const void* hw1, const void* hb1, const void* hw2, const void* hb2,
    const void* xw1, const void* xb1, const void* xw2, const void* xb2,
    float* __restrict__ wbuf, float* __restrict__ x,
    unsigned short* __restrict__ h_bf, int* __restrict__ cnt,
    int* __restrict__ flag)
{
    const int bf = detect_bf(pos);
    const int tid = blockIdx.x * blockDim.x + threadIdx.x;
    if (tid == 0) *flag = bf;
    const int stride = gridDim.x * blockDim.x;

    for (int n = tid; n < NN; n += stride) {
        x[n * 4 + 0] = ldf(pos, n * 3 + 0, bf);
        x[n * 4 + 1] = ldf(pos, n * 3 + 1, bf);
        x[n * 4 + 2] = ldf(pos, n * 3 + 2, bf);
        x[n * 4 + 3] = 0.f;
    }
    for (int i = tid; i < 16512; i += stride) wbuf[EW1_O + i] = ldf(ew1, i, bf);
    for (int i = tid; i < 128; i += stride) wbuf[EB1_O + i] = ldf(eb1, i, bf);
    for (int i = tid; i < 8192; i += stride) wbuf[EW2_O + i] = ldf(ew2, i, bf);
    for (int i = tid; i < 128; i += stride) wbuf[EB2_O + i] = ldf(eb2, i, bf);
    for (int i = tid; i < 16384; i += stride) wbuf[HW1_O + i] = ldf(hw1, i, bf);
    for (int i = tid; i < 128; i += stride) wbuf[HB1_O + i] = ldf(hb1, i, bf);
    for (int i = tid; i < 8192; i += stride) wbuf[HW2_O + i] = ldf(hw2, i, bf);
    for (int i = tid; i < 128; i += stride) wbuf[HB2_O + i] = ldf(hb2, i, bf);
    for (int i = tid; i < 8192; i += stride) wbuf[XW1_O + i] = ldf(xw1, i, bf);
    for (int i = tid; i < 128; i += stride) wbuf[XB1_O + i] = ldf(xb1, i, bf);
    for (int i = tid; i < 128; i += stride) wbuf[XW2_O + i] = ldf(xw2, i, bf);
    for (int i = tid; i < 2; i += stride) wbuf[XB2_O + i] = ldf(xb2, i, bf);

    // init h_bf directly from raw emb
    for (int i = tid; i < NN * HD; i += stride) {
        int a = an[i >> 6];
        a = (a < 0) ? 0 : (a > 99 ? 99 : a);
        h_bf[i] = f2bf(ldf(emb, a * HD + (i & 63), bf));
    }
    // histogram of dst
    for (int e = tid; e < NE; e += stride) {
        int d = ei[NE + e];
        d = (d < 0) ? 0 : (d >= NN ? NN - 1 : d);
        atomicAdd(&cnt[d], 1);
    }
}

// -------------------------------------------------------------- sort --------
__global__ __launch_bounds__(256) void scan1_kernel(
    const int* __restrict__ cnt, int* __restrict__ incl, int* __restrict__ csum)
{
    __shared__ int s[256];
    const int t = threadIdx.x, b = blockIdx.x, i = b * 256 + t;
    s[t] = cnt[i];
    __syncthreads();
#pragma unroll
    for (int o = 1; o < 256; o <<= 1) {
        const int u = (t >= o) ? s[t - o] : 0;
        __syncthreads();
        s[t] += u;
        __syncthreads();
    }
    incl[i] = s[t];
    if (t == 255) csum[b] = s[255];
}

__global__ void scan2_kernel(int* __restrict__ csum) {
    __shared__ int s[256];
    const int t = threadIdx.x;
    s[t] = (t < NCH) ? csum[t] : 0;
    __syncthreads();
#pragma unroll
    for (int o = 1; o < 256; o <<= 1) {
        const int u = (t >= o) ? s[t - o] : 0;
        __syncthreads();
        s[t] += u;
        __syncthreads();
    }
    if (t < NCH) csum[t] = s[t];
}

__global__ __launch_bounds__(256) void scan3_kernel(
    int* __restrict__ cnt, const int* __restrict__ incl, const int* __restrict__ csum)
{
    const int t = threadIdx.x, b = blockIdx.x, i = b * 256 + t;
    const int off = (b > 0) ? csum[b - 1] : 0;
    cnt[i] = incl[i] + off - cnt[i];
}

__global__ __launch_bounds__(256) void scatter_kernel(
    const int* __restrict__ ei, int* __restrict__ cur, int2* __restrict__ pair)
{
    const int stride = gridDim.x * blockDim.x;
    for (int e = blockIdx.x * blockDim.x + threadIdx.x; e < NE; e += stride) {
        int s = ei[e];
        int d = ei[NE + e];
        s = (s < 0) ? 0 : (s >= NN ? NN - 1 : s);
        d = (d < 0) ? 0 : (d >= NN ? NN - 1 : d);
        const int p = atomicAdd(&cur[d], 1);
        pair[p] = make_int2(s, d);
    }
}

// -------------------------------------------------------------- edge MFMA ---
// One wave = 16 dst-sorted edges. 512-thread blocks (8 waves) share the
// 24 KB weight LDS -> 3 blocks/CU = 24 waves/CU. Only ONE register B-frag
// set (bw2) — two sets spill (R7/R8 evidence). m stored RNE.
__global__ __launch_bounds__(512, 6) void edge_mfma_kernel(
    const unsigned short* __restrict__ h_bf, const float* __restrict__ x,
    const int2* __restrict__ pair,
    const float* __restrict__ w1, const float* __restrict__ b1,
    const float* __restrict__ b2,
    const float* __restrict__ w2,
    const float* __restrict__ xw1, const float* __restrict__ xb1,
    const float* __restrict__ xw2, const float* __restrict__ xb2,
    float* __restrict__ m_agg, float* __restrict__ x_agg)
{
    __shared__ unsigned short s_w1p[4 * 4 * 64 * 8];   // 16 KB
    __shared__ unsigned short s_xw1p[2 * 4 * 64 * 8];  // 8 KB
    __shared__ unsigned short s_act[8][16 * ROWP];     // 18 KB
    __shared__ float s_xd[8][16][4];                   // 2 KB
    __shared__ float s_wv[8][16];                      // 512 B

    const int tid = threadIdx.x;
    for (int p = tid; p < 4 * 4 * 64 * 8; p += 512) {
        const int j = p & 7, ln = (p >> 3) & 63, nt = (p >> 9) & 3, kc = p >> 11;
        const int k = kc * 32 + (ln >> 4) * 8 + j, n = nt * 16 + (ln & 15);
        s_w1p[p] = f2bf(w1[k * 64 + n]);
    }
    for (int p = tid; p < 2 * 4 * 64 * 8; p += 512) {
        const int j = p & 7, ln = (p >> 3) & 63, nt = (p >> 9) & 3, kc = p >> 11;
        const int k = kc * 32 + (ln >> 4) * 8 + j, n = nt * 16 + (ln & 15);
        s_xw1p[p] = f2bf(xw1[k * 64 + n]);
    }
    __syncthreads();

    const int lane = tid & 63;
    const int wid = tid >> 6;           // 0..7
    const int l15 = lane & 15;
    const int q = lane >> 4;

    // single register-held B-frag set (phi_e L2) — one set is spill-free
    s16x8 bw2[2][4];
#pragma unroll
    for (int kc = 0; kc < 2; ++kc)
#pragma unroll
        for (int nt = 0; nt < 4; ++nt)
#pragma unroll
            for (int j = 0; j < 8; ++j)
                bw2[kc][nt][j] = (short)f2bf(w2[(kc * 32 + q * 8 + j) * 64 + nt * 16 + l15]);

    float b1v[4], b2v[4], xb1v[4], xw2v[4], wrv[4];
#pragma unroll
    for (int nt = 0; nt < 4; ++nt) {
        b1v[nt] = b1[nt * 16 + l15];
        b2v[nt] = b2[nt * 16 + l15];
        xb1v[nt] = xb1[nt * 16 + l15];
        xw2v[nt] = xw2[nt * 16 + l15];
        wrv[nt] = w1[128 * 64 + nt * 16 + l15];
    }
    const float xb2v = xb2[0];

    unsigned short* act = s_act[wid];
    float (*xd)[4] = s_xd[wid];
    float* wv = s_wv[wid];

    const int gwave = (blockIdx.x << 3) + wid;
    const int nwaves = gridDim.x << 3;

    for (int t = gwave; t < NT_E; t += nwaves) {
        const int e0 = t * 16;
        const int2 e = pair[e0 + l15];
        const int sidx = e.x, didx = e.y;
        const f32x4 xs = *(const f32x4*)&x[sidx * 4];
        const f32x4 xdv = *(const f32x4*)&x[didx * 4];
        const float ax = xs[0] - xdv[0];
        const float ay = xs[1] - xdv[1];
        const float az = xs[2] - xdv[2];
        const float rme = sqrtf(ax * ax + ay * ay + az * az);
        if (lane < 16) { xd[lane][0] = ax; xd[lane][1] = ay; xd[lane][2] = az; }

        const s16x8 a_hd0 = *(const s16x8*)&h_bf[didx * 64 + q * 8];
        const s16x8 a_hd1 = *(const s16x8*)&h_bf[didx * 64 + 32 + q * 8];
        const s16x8 a_hs0 = *(const s16x8*)&h_bf[sidx * 64 + q * 8];
        const s16x8 a_hs1 = *(const s16x8*)&h_bf[sidx * 64 + 32 + q * 8];

        // ---- phi_e layer 1 ----
        f32x4 acc[4];
#pragma unroll
        for (int nt = 0; nt < 4; ++nt) acc[nt] = (f32x4){0.f, 0.f, 0.f, 0.f};
#pragma unroll
        for (int kc = 0; kc < 4; ++kc) {
            const s16x8 a = (kc == 0) ? a_hd0 : (kc == 1) ? a_hd1 : (kc == 2) ? a_hs0 : a_hs1;
#pragma unroll
            for (int nt = 0; nt < 4; ++nt) {
                const s16x8 b = *(const s16x8*)&s_w1p[((kc * 4 + nt) * 64 + lane) * 8];
                acc[nt] = __builtin_amdgcn_mfma_f32_16x16x32_bf16(a, b, acc[nt], 0, 0, 0);
            }
        }
        float rv[4];
#pragma unroll
        for (int r = 0; r < 4; ++r) rv[r] = __shfl(rme, q * 4 + r, 64);
#pragma unroll
        for (int nt = 0; nt < 4; ++nt)
#pragma unroll
            for (int r = 0; r < 4; ++r) {
                const float v = silu(acc[nt][r] + b1v[nt] + rv[r] * wrv[nt]);
                act[(q * 4 + r) * ROWP + nt * 16 + l15] = f2bf_t(v);
            }

        // ---- phi_e layer 2 (B in registers) -> m (RNE: feeds 16-deep sums) -
        f32x4 acc2[4];
#pragma unroll
        for (int nt = 0; nt < 4; ++nt) acc2[nt] = (f32x4){0.f, 0.f, 0.f, 0.f};
#pragma unroll
        for (int kc = 0; kc < 2; ++kc) {
            const s16x8 a = *(const s16x8*)&act[l15 * ROWP + kc * 32 + q * 8];
#pragma unroll
            for (int nt = 0; nt < 4; ++nt)
                acc2[nt] = __builtin_amdgcn_mfma_f32_16x16x32_bf16(a, bw2[kc][nt], acc2[nt], 0, 0, 0);
        }
#pragma unroll
        for (int nt = 0; nt < 4; ++nt)
#pragma unroll
            for (int r = 0; r < 4; ++r) {
                const float v = silu(acc2[nt][r] + b2v[nt]);
                act[(q * 4 + r) * ROWP + nt * 16 + l15] = f2bf(v);
            }

        // ---- phi_x layer 1 (B from LDS) ----
        f32x4 xacc[4];
#pragma unroll
        for (int nt = 0; nt < 4; ++nt) xacc[nt] = (f32x4){0.f, 0.f, 0.f, 0.f};
#pragma unroll
        for (int kc = 0; kc < 2; ++kc) {
            const s16x8 a = *(const s16x8*)&act[l15 * ROWP + kc * 32 + q * 8];
#pragma unroll
            for (int nt = 0; nt < 4; ++nt) {
                const s16x8 b = *(const s16x8*)&s_xw1p[((kc * 4 + nt) * 64 + lane) * 8];
                xacc[nt] = __builtin_amdgcn_mfma_f32_16x16x32_bf16(a, b, xacc[nt], 0, 0, 0);
            }
        }
        // ---- phi_x layer 2 ----
        float ssum[4];
#pragma unroll
        for (int r = 0; r < 4; ++r) {
            float s = 0.f;
#pragma unroll
            for (int nt = 0; nt < 4; ++nt)
                s += silu(xacc[nt][r] + xb1v[nt]) * xw2v[nt];
            ssum[r] = s;
        }
#pragma unroll
        for (int off = 1; off < 16; off <<= 1)
#pragma unroll
            for (int r = 0; r < 4; ++r) ssum[r] += __shfl_xor(ssum[r], off, 64);
        if (l15 == 0) {
#pragma unroll
            for (int r = 0; r < 4; ++r) wv[q * 4 + r] = ssum[r] + xb2v;
        }

        // ---- segmented per-dst aggregation ----
        int dstv[17];
#pragma unroll
        for (int rr = 0; rr < 16; ++rr) dstv[rr] = __shfl(didx, rr, 64);
        dstv[16] = -1;

        float macc = 0.f;
#pragma unroll
        for (int rr = 0; rr < 16; ++rr) {
            macc += bf2f(act[rr * ROWP + lane]);
            if (dstv[rr + 1] != dstv[rr]) {
                atomicAdd(&m_agg[dstv[rr] * 64 + lane], macc);
                macc = 0.f;
            }
        }
        if (lane < 3) {
            float xac = 0.f;
#pragma unroll
            for (int rr = 0; rr < 16; ++rr) {
                xac += wv[rr] * xd[rr][lane];
                if (dstv[rr + 1] != dstv[rr]) {
                    atomicAdd(&x_agg[dstv[rr] * 3 + lane], xac);
                    xac = 0.f;
                }
            }
        }
    }
}

// -------------------------------------------------------------- node MFMA ---
// h bf16 residual; w2 in registers (single set); zeroes m_agg/x_agg after
// reading them (replaces next layer's memsets).
__global__ __launch_bounds__(512, 6) void node_mfma_kernel(
    float* __restrict__ x,
    float* __restrict__ m_agg, float* __restrict__ x_agg,
    const float* __restrict__ w1, const float* __restrict__ b1,   // [128][64]
    const float* __restrict__ w2, const float* __restrict__ b2,   // [64][64]
    unsigned short* __restrict__ h_bf,
    void* __restrict__ outv, const int* __restrict__ flag)
{
    __shared__ unsigned short s_w1p[4 * 4 * 64 * 8];   // 16 KB
    __shared__ unsigned short s_act[8][16 * ROWP];     // 18 KB

    const int tid = threadIdx.x;
    for (int p = tid; p < 4 * 4 * 64 * 8; p += 512) {
        const int j = p & 7, ln = (p >> 3) & 63, nt = (p >> 9) & 3, kc = p >> 11;
        const int k = kc * 32 + (ln >> 4) * 8 + j, n = nt * 16 + (ln & 15);
        s_w1p[p] = f2bf(w1[k * 64 + n]);
    }
    __syncthreads();

    const int bf = flag ? *flag : 1;
    const int lane = tid & 63;
    const int wid = tid >> 6;
    const int l15 = lane & 15;
    const int q = lane >> 4;

    // x update (+ optional out); zero x_agg after read
    for (int n = blockIdx.x * 512 + tid; n < NN; n += gridDim.x * 512) {
#pragma unroll
        for (int c = 0; c < 3; ++c) {
            const float xn = x[n * 4 + c] + x_agg[n * 3 + c];
            x_agg[n * 3 + c] = 0.f;
            x[n * 4 + c] = xn;
            if (outv) {
                if (bf) ((unsigned short*)outv)[NN * HD + n * 3 + c] = f2bf(xn);
                else ((float*)outv)[NN * HD + n * 3 + c] = xn;
            }
        }
    }

    s16x8 bw2[2][4];
#pragma unroll
    for (int kc = 0; kc < 2; ++kc)
#pragma unroll
        for (int nt = 0; nt < 4; ++nt)
#pragma unroll
            for (int j = 0; j < 8; ++j)
                bw2[kc][nt][j] = (short)f2bf(w2[(kc * 32 + q * 8 + j) * 64 + nt * 16 + l15]);

    float b1v[4], b2v[4];
#pragma unroll
    for (int nt = 0; nt < 4; ++nt) {
        b1v[nt] = b1[nt * 16 + l15];
        b2v[nt] = b2[nt * 16 + l15];
    }
    unsigned short* act = s_act[wid];
    const f32x4 zero4 = (f32x4){0.f, 0.f, 0.f, 0.f};

    for (int t = (blockIdx.x << 3) + wid; t < NT_N; t += gridDim.x << 3) {
        const int n = t * 16 + l15;
        const s16x8 a0 = *(const s16x8*)&h_bf[n * 64 + q * 8];
        const s16x8 a1 = *(const s16x8*)&h_bf[n * 64 + 32 + q * 8];
        const f32x4 m0 = *(const f32x4*)&m_agg[n * 64 + q * 8];
        const f32x4 m1 = *(const f32x4*)&m_agg[n * 64 + q * 8 + 4];
        const f32x4 m2 = *(const f32x4*)&m_agg[n * 64 + 32 + q * 8];
        const f32x4 m3 = *(const f32x4*)&m_agg[n * 64 + 32 + q * 8 + 4];
        // zero after read (replaces next layer's memset; disjoint coverage)
        *(f32x4*)&m_agg[n * 64 + q * 8] = zero4;
        *(f32x4*)&m_agg[n * 64 + q * 8 + 4] = zero4;
        *(f32x4*)&m_agg[n * 64 + 32 + q * 8] = zero4;
        *(f32x4*)&m_agg[n * 64 + 32 + q * 8 + 4] = zero4;
        s16x8 a2, a3;
#pragma unroll
        for (int j = 0; j < 4; ++j) {
            a2[j] = (short)f2bf(m0[j]); a2[4 + j] = (short)f2bf(m1[j]);
            a3[j] = (short)f2bf(m2[j]); a3[4 + j] = (short)f2bf(m3[j]);
        }

        f32x4 acc[4];
#pragma unroll
        for (int nt = 0; nt < 4; ++nt) acc[nt] = zero4;
#pragma unroll
        for (int kc = 0; kc < 4; ++kc) {
            const s16x8 a = (kc == 0) ? a0 : (kc == 1) ? a1 : (kc == 2) ? a2 : a3;
#pragma unroll
            for (int nt = 0; nt < 4; ++nt) {
                const s16x8 b = *(const s16x8*)&s_w1p[((kc * 4 + nt) * 64 + lane) * 8];
                acc[nt] = __builtin_amdgcn_mfma_f32_16x16x32_bf16(a, b, acc[nt], 0, 0, 0);
            }
        }
#pragma unroll
        for (int nt = 0; nt < 4; ++nt)
#pragma unroll
            for (int r = 0; r < 4; ++r)
                act[(q * 4 + r) * ROWP + nt * 16 + l15] = f2bf_t(silu(acc[nt][r] + b1v[nt]));

        f32x4 acc2[4];
#pragma unroll
        for (int nt = 0; nt < 4; ++nt) acc2[nt] = zero4;
#pragma unroll
        for (int kc = 0; kc < 2; ++kc) {
            const s16x8 a = *(const s16x8*)&act[l15 * ROWP + kc * 32 + q * 8];
#pragma unroll
            for (int nt = 0; nt < 4; ++nt)
                acc2[nt] = __builtin_amdgcn_mfma_f32_16x16x32_bf16(a, bw2[kc][nt], acc2[nt], 0, 0, 0);
        }
#pragma unroll
        for (int nt = 0; nt < 4; ++nt)
#pragma unroll
            for (int r = 0; r < 4; ++r) {
                const int row = t * 16 + q * 4 + r, col = nt * 16 + l15;
                const float hn = bf2f(h_bf[row * 64 + col]) + acc2[nt][r] + b2v[nt];
                h_bf[row * 64 + col] = f2bf(hn);
                if (outv) {
                    if (bf) ((unsigned short*)outv)[row * 64 + col] = f2bf(hn);
                    else ((float*)outv)[row * 64 + col] = hn;
                }
            }
    }
}

// -------------------------------------------------------------- launch ------
extern "C" void kernel_launch(void* const* d_in, const int* in_sizes, int n_in,
                              void* d_out, int out_size, void* d_ws, size_t ws_size,
                              hipStream_t stream) {
    const int* an = (const int*)d_in[0];
    const void* pos = d_in[1];
    const int* ei = (const int*)d_in[2];

    int wi = 4;
    if (n_in > 4 && in_sizes[4] == 6400) wi = 4;
    else if (n_in > 3 && in_sizes[3] == 6400) wi = 3;
    const void* emb = d_in[wi];
    const void* e_w1 = d_in[wi + 1];
    const void* e_b1 = d_in[wi + 2];
    const void* e_w2 = d_in[wi + 3];
    const void* e_b2 = d_in[wi + 4];
    const void* h_w1 = d_in[wi + 5];
    const void* h_b1 = d_in[wi + 6];
    const void* h_w2 = d_in[wi + 7];
    const void* h_b2 = d_in[wi + 8];
    const void* x_w1 = d_in[wi + 9];
    const void* x_b1 = d_in[wi + 10];
    const void* x_w2 = d_in[wi + 11];
    const void* x_b2 = d_in[wi + 12];

    float* ws = (float*)d_ws;
    int* flag = (int*)(ws + FLAG_OFF);
    float* wbuf = ws + WB_OFF;
    float* x = ws + X_OFF;
    float* m_agg = ws + MAGG_OFF;
    float* x_agg = ws + XAGG_OFF;
    unsigned short* h_bf = (unsigned short*)(ws + HBF_OFF);
    int* cnt = (int*)(ws + CNT_OFF);
    int* csum = (int*)(ws + CSUM_OFF);
    int* incl = (int*)(ws + INCL_OFF);
    int2* pair = (int2*)(ws + PAIR_OFF);

    hipMemsetAsync(cnt, 0, NCH * 256 * sizeof(int), stream);
    prep_kernel<<<784, 256, 0, stream>>>(an, pos, ei, emb,
        e_w1, e_b1, e_w2, e_b2, h_w1, h_b1, h_w2, h_b2,
        x_w1, x_b1, x_w2, x_b2, wbuf, x, h_bf, cnt, flag);
    scan1_kernel<<<NCH, 256, 0, stream>>>(cnt, incl, csum);
    scan2_kernel<<<1, 256, 0, stream>>>(csum);
    scan3_kernel<<<NCH, 256, 0, stream>>>(cnt, incl, csum);
    scatter_kernel<<<512, 256, 0, stream>>>(ei, cnt, pair);

    hipMemsetAsync(m_agg, 0, (size_t)NN * HD * sizeof(float), stream);
    hipMemsetAsync(x_agg, 0, (size_t)NN * 3 * sizeof(float), stream);

    for (int l = 0; l < NL; ++l) {
        edge_mfma_kernel<<<768, 512, 0, stream>>>(h_bf, x, pair,
            wbuf + EW1_O + l * 129 * 64, wbuf + EB1_O + l * 64,
            wbuf + EB2_O + l * 64,
            wbuf + EW2_O + l * 64 * 64,
            wbuf + XW1_O + l * 64 * 64, wbuf + XB1_O + l * 64,
            wbuf + XW2_O + l * 64, wbuf + XB2_O + l,
            m_agg, x_agg);

        void* out_p = (l == NL - 1) ? d_out : nullptr;
        node_mfma_kernel<<<392, 512, 0, stream>>>(x, m_agg, x_agg,
            wbuf + HW1_O + l * 128 * 64, wbuf + HB1_O + l * 64,
            wbuf + HW2_O + l * 64 * 64, wbuf + HB2_O + l * 64,
            h_bf, out_p, flag);
    }
}

// Round 11
// 461.876 us; speedup vs baseline: 1.0773x; 1.0773x over previous
//
#include <hip/hip_runtime.h>

#define NN 50000
#define NE 800000
#define HD 64
#define NL 2
#define NT_E (NE / 16)   // 50000 edge tiles
#define NT_N (NN / 16)   // 3125 node tiles
#define NCH 196          // scan chunks: 196*256 = 50176 >= NN+1

typedef __attribute__((ext_vector_type(4))) float f32x4;
typedef __attribute__((ext_vector_type(8))) short s16x8;

// ---- d_ws layout (float element offsets) ----
#define FLAG_OFF 0
#define WB_OFF   16
#define EMB_O 0
#define EW1_O 6400
#define EB1_O 22912
#define EW2_O 23040
#define EB2_O 31232
#define HW1_O 31360
#define HB1_O 47744
#define HW2_O 47872
#define HB2_O 56064
#define XW1_O 56192
#define XB1_O 64384
#define XW2_O 64512
#define XB2_O 64640
#define X_OFF    (WB_OFF + 64656)              // fp32 x, padded [NN][4]
#define MAGG_OFF (X_OFF + NN * 4)
#define XAGG_OFF (MAGG_OFF + NN * HD)
#define HBF_OFF  (XAGG_OFF + NN * 3)           // ushort[NN*64]
#define CNT_OFF  (HBF_OFF + NN * 32)
#define CSUM_OFF (CNT_OFF + NCH * 256)
#define INCL_OFF (CSUM_OFF + 256)
#define PAIR_OFF (INCL_OFF + NCH * 256)        // int2[NE]

#define ROWP 72

__device__ __forceinline__ float bf2f(unsigned short u) {
    return __uint_as_float(((unsigned int)u) << 16);
}
__device__ __forceinline__ unsigned short f2bf(float f) {      // RNE
    unsigned int i = __float_as_uint(f);
    i += 0x7fffu + ((i >> 16) & 1u);
    return (unsigned short)(i >> 16);
}
__device__ __forceinline__ unsigned short f2bf_t(float f) {    // trunc (GEMM temps)
    return (unsigned short)(__float_as_uint(f) >> 16);
}
__device__ __forceinline__ float silu(float v) {               // no div sequence
    const float e = __expf(-v);
    return v * __builtin_amdgcn_rcpf(1.0f + e);
}
__device__ __forceinline__ float ldf(const void* p, int i, int bf) {
    return bf ? bf2f(((const unsigned short*)p)[i]) : ((const float*)p)[i];
}
// per-wave bf16-vs-fp32 input detection (all waves agree; no global dep)
__device__ __forceinline__ int detect_bf(const void* pos) {
    const int lane = threadIdx.x & 63;
    const float v = bf2f(((const unsigned short*)pos)[2 * lane]);
    const float a = fabsf(v);
    const unsigned long long m = __ballot(a >= 1e-6f && a <= 1e6f);
    return (__popcll(m) >= 32) ? 1 : 0;
}

// -------------------------------------------------------------- prep --------
// Fused: detect + convert(x, weights) + init_h + hist. cnt must be pre-zeroed.
__global__ __launch_bounds__(256) void prep_kernel(
    const int* __restrict__ an, const void* pos, const int* __restrict__ ei,
    const void* emb,
    const void* ew1, const void* eb1, const void* ew2, const void* eb2,
    const void* hw1, const void* hb1, const void* hw2, const void* hb2,
    const void* xw1, const void* xb1, const void* xw2, const void* xb2,
    float* __restrict__ wbuf, float* __restrict__ x,
    unsigned short* __restrict__ h_bf, int* __restrict__ cnt,
    int* __restrict__ flag)
{
    const int bf = detect_bf(pos);
    const int tid = blockIdx.x * blockDim.x + threadIdx.x;
    if (tid == 0) *flag = bf;
    const int stride = gridDim.x * blockDim.x;

    for (int n = tid; n < NN; n += stride) {
        x[n * 4 + 0] = ldf(pos, n * 3 + 0, bf);
        x[n * 4 + 1] = ldf(pos, n * 3 + 1, bf);
        x[n * 4 + 2] = ldf(pos, n * 3 + 2, bf);
        x[n * 4 + 3] = 0.f;
    }
    for (int i = tid; i < 16512; i += stride) wbuf[EW1_O + i] = ldf(ew1, i, bf);
    for (int i = tid; i < 128; i += stride) wbuf[EB1_O + i] = ldf(eb1, i, bf);
    for (int i = tid; i < 8192; i += stride) wbuf[EW2_O + i] = ldf(ew2, i, bf);
    for (int i = tid; i < 128; i += stride) wbuf[EB2_O + i] = ldf(eb2, i, bf);
    for (int i = tid; i < 16384; i += stride) wbuf[HW1_O + i] = ldf(hw1, i, bf);
    for (int i = tid; i < 128; i += stride) wbuf[HB1_O + i] = ldf(hb1, i, bf);
    for (int i = tid; i < 8192; i += stride) wbuf[HW2_O + i] = ldf(hw2, i, bf);
    for (int i = tid; i < 128; i += stride) wbuf[HB2_O + i] = ldf(hb2, i, bf);
    for (int i = tid; i < 8192; i += stride) wbuf[XW1_O + i] = ldf(xw1, i, bf);
    for (int i = tid; i < 128; i += stride) wbuf[XB1_O + i] = ldf(xb1, i, bf);
    for (int i = tid; i < 128; i += stride) wbuf[XW2_O + i] = ldf(xw2, i, bf);
    for (int i = tid; i < 2; i += stride) wbuf[XB2_O + i] = ldf(xb2, i, bf);

    // init h_bf directly from raw emb
    for (int i = tid; i < NN * HD; i += stride) {
        int a = an[i >> 6];
        a = (a < 0) ? 0 : (a > 99 ? 99 : a);
        h_bf[i] = f2bf(ldf(emb, a * HD + (i & 63), bf));
    }
    // histogram of dst
    for (int e = tid; e < NE; e += stride) {
        int d = ei[NE + e];
        d = (d < 0) ? 0 : (d >= NN ? NN - 1 : d);
        atomicAdd(&cnt[d], 1);
    }
}

// -------------------------------------------------------------- sort --------
__global__ __launch_bounds__(256) void scan1_kernel(
    const int* __restrict__ cnt, int* __restrict__ incl, int* __restrict__ csum)
{
    __shared__ int s[256];
    const int t = threadIdx.x, b = blockIdx.x, i = b * 256 + t;
    s[t] = cnt[i];
    __syncthreads();
#pragma unroll
    for (int o = 1; o < 256; o <<= 1) {
        const int u = (t >= o) ? s[t - o] : 0;
        __syncthreads();
        s[t] += u;
        __syncthreads();
    }
    incl[i] = s[t];
    if (t == 255) csum[b] = s[255];
}

__global__ void scan2_kernel(int* __restrict__ csum) {
    __shared__ int s[256];
    const int t = threadIdx.x;
    s[t] = (t < NCH) ? csum[t] : 0;
    __syncthreads();
#pragma unroll
    for (int o = 1; o < 256; o <<= 1) {
        const int u = (t >= o) ? s[t - o] : 0;
        __syncthreads();
        s[t] += u;
        __syncthreads();
    }
    if (t < NCH) csum[t] = s[t];
}

__global__ __launch_bounds__(256) void scan3_kernel(
    int* __restrict__ cnt, const int* __restrict__ incl, const int* __restrict__ csum)
{
    const int t = threadIdx.x, b = blockIdx.x, i = b * 256 + t;
    const int off = (b > 0) ? csum[b - 1] : 0;
    cnt[i] = incl[i] + off - cnt[i];
}

__global__ __launch_bounds__(256) void scatter_kernel(
    const int* __restrict__ ei, int* __restrict__ cur, int2* __restrict__ pair)
{
    const int stride = gridDim.x * blockDim.x;
    for (int e = blockIdx.x * blockDim.x + threadIdx.x; e < NE; e += stride) {
        int s = ei[e];
        int d = ei[NE + e];
        s = (s < 0) ? 0 : (s >= NN ? NN - 1 : s);
        d = (d < 0) ? 0 : (d >= NN ? NN - 1 : d);
        const int p = atomicAdd(&cur[d], 1);
        pair[p] = make_int2(s, d);
    }
}

// -------------------------------------------------------------- edge MFMA ---
// PROVEN R6 CONFIG: 256 threads, launch_bounds(256,4), ONE register B-frag
// set (bw2), xw1 in LDS, RNE m. VGPR=64, no spill (FETCH~66MB, WRITE~28MB).
// Do NOT tighten the VGPR cap or add a 2nd fragment set — spills (R7/R8/R10).
__global__ __launch_bounds__(256, 4) void edge_mfma_kernel(
    const unsigned short* __restrict__ h_bf, const float* __restrict__ x,
    const int2* __restrict__ pair,
    const float* __restrict__ w1, const float* __restrict__ b1,
    const float* __restrict__ b2,
    const float* __restrict__ w2,
    const float* __restrict__ xw1, const float* __restrict__ xb1,
    const float* __restrict__ xw2, const float* __restrict__ xb2,
    float* __restrict__ m_agg, float* __restrict__ x_agg)
{
    __shared__ unsigned short s_w1p[4 * 4 * 64 * 8];   // 16 KB
    __shared__ unsigned short s_xw1p[2 * 4 * 64 * 8];  // 8 KB
    __shared__ unsigned short s_act[4][16 * ROWP];     // 9 KB
    __shared__ float s_xd[4][16][4];                   // 1 KB
    __shared__ float s_wv[4][16];                      // 256 B

    const int tid = threadIdx.x;
    for (int p = tid; p < 4 * 4 * 64 * 8; p += 256) {
        const int j = p & 7, ln = (p >> 3) & 63, nt = (p >> 9) & 3, kc = p >> 11;
        const int k = kc * 32 + (ln >> 4) * 8 + j, n = nt * 16 + (ln & 15);
        s_w1p[p] = f2bf(w1[k * 64 + n]);
    }
    for (int p = tid; p < 2 * 4 * 64 * 8; p += 256) {
        const int j = p & 7, ln = (p >> 3) & 63, nt = (p >> 9) & 3, kc = p >> 11;
        const int k = kc * 32 + (ln >> 4) * 8 + j, n = nt * 16 + (ln & 15);
        s_xw1p[p] = f2bf(xw1[k * 64 + n]);
    }
    __syncthreads();

    const int lane = tid & 63;
    const int wid = tid >> 6;
    const int l15 = lane & 15;
    const int q = lane >> 4;

    // single register-held B-frag set (phi_e L2) — one set is spill-free
    s16x8 bw2[2][4];
#pragma unroll
    for (int kc = 0; kc < 2; ++kc)
#pragma unroll
        for (int nt = 0; nt < 4; ++nt)
#pragma unroll
            for (int j = 0; j < 8; ++j)
                bw2[kc][nt][j] = (short)f2bf(w2[(kc * 32 + q * 8 + j) * 64 + nt * 16 + l15]);

    float b1v[4], b2v[4], xb1v[4], xw2v[4], wrv[4];
#pragma unroll
    for (int nt = 0; nt < 4; ++nt) {
        b1v[nt] = b1[nt * 16 + l15];
        b2v[nt] = b2[nt * 16 + l15];
        xb1v[nt] = xb1[nt * 16 + l15];
        xw2v[nt] = xw2[nt * 16 + l15];
        wrv[nt] = w1[128 * 64 + nt * 16 + l15];
    }
    const float xb2v = xb2[0];

    unsigned short* act = s_act[wid];
    float (*xd)[4] = s_xd[wid];
    float* wv = s_wv[wid];

    const int gwave = (blockIdx.x << 2) + wid;
    const int nwaves = gridDim.x << 2;

    for (int t = gwave; t < NT_E; t += nwaves) {
        const int e0 = t * 16;
        const int2 e = pair[e0 + l15];
        const int sidx = e.x, didx = e.y;
        const f32x4 xs = *(const f32x4*)&x[sidx * 4];
        const f32x4 xdv = *(const f32x4*)&x[didx * 4];
        const float ax = xs[0] - xdv[0];
        const float ay = xs[1] - xdv[1];
        const float az = xs[2] - xdv[2];
        const float rme = sqrtf(ax * ax + ay * ay + az * az);
        if (lane < 16) { xd[lane][0] = ax; xd[lane][1] = ay; xd[lane][2] = az; }

        const s16x8 a_hd0 = *(const s16x8*)&h_bf[didx * 64 + q * 8];
        const s16x8 a_hd1 = *(const s16x8*)&h_bf[didx * 64 + 32 + q * 8];
        const s16x8 a_hs0 = *(const s16x8*)&h_bf[sidx * 64 + q * 8];
        const s16x8 a_hs1 = *(const s16x8*)&h_bf[sidx * 64 + 32 + q * 8];

        // ---- phi_e layer 1 ----
        f32x4 acc[4];
#pragma unroll
        for (int nt = 0; nt < 4; ++nt) acc[nt] = (f32x4){0.f, 0.f, 0.f, 0.f};
#pragma unroll
        for (int kc = 0; kc < 4; ++kc) {
            const s16x8 a = (kc == 0) ? a_hd0 : (kc == 1) ? a_hd1 : (kc == 2) ? a_hs0 : a_hs1;
#pragma unroll
            for (int nt = 0; nt < 4; ++nt) {
                const s16x8 b = *(const s16x8*)&s_w1p[((kc * 4 + nt) * 64 + lane) * 8];
                acc[nt] = __builtin_amdgcn_mfma_f32_16x16x32_bf16(a, b, acc[nt], 0, 0, 0);
            }
        }
        float rv[4];
#pragma unroll
        for (int r = 0; r < 4; ++r) rv[r] = __shfl(rme, q * 4 + r, 64);
#pragma unroll
        for (int nt = 0; nt < 4; ++nt)
#pragma unroll
            for (int r = 0; r < 4; ++r) {
                const float v = silu(acc[nt][r] + b1v[nt] + rv[r] * wrv[nt]);
                act[(q * 4 + r) * ROWP + nt * 16 + l15] = f2bf_t(v);
            }

        // ---- phi_e layer 2 (B in registers) -> m (RNE: feeds 16-deep sums) -
        f32x4 acc2[4];
#pragma unroll
        for (int nt = 0; nt < 4; ++nt) acc2[nt] = (f32x4){0.f, 0.f, 0.f, 0.f};
#pragma unroll
        for (int kc = 0; kc < 2; ++kc) {
            const s16x8 a = *(const s16x8*)&act[l15 * ROWP + kc * 32 + q * 8];
#pragma unroll
            for (int nt = 0; nt < 4; ++nt)
                acc2[nt] = __builtin_amdgcn_mfma_f32_16x16x32_bf16(a, bw2[kc][nt], acc2[nt], 0, 0, 0);
        }
#pragma unroll
        for (int nt = 0; nt < 4; ++nt)
#pragma unroll
            for (int r = 0; r < 4; ++r) {
                const float v = silu(acc2[nt][r] + b2v[nt]);
                act[(q * 4 + r) * ROWP + nt * 16 + l15] = f2bf(v);
            }

        // ---- phi_x layer 1 (B from LDS) ----
        f32x4 xacc[4];
#pragma unroll
        for (int nt = 0; nt < 4; ++nt) xacc[nt] = (f32x4){0.f, 0.f, 0.f, 0.f};
#pragma unroll
        for (int kc = 0; kc < 2; ++kc) {
            const s16x8 a = *(const s16x8*)&act[l15 * ROWP + kc * 32 + q * 8];
#pragma unroll
            for (int nt = 0; nt < 4; ++nt) {
                const s16x8 b = *(const s16x8*)&s_xw1p[((kc * 4 + nt) * 64 + lane) * 8];
                xacc[nt] = __builtin_amdgcn_mfma_f32_16x16x32_bf16(a, b, xacc[nt], 0, 0, 0);
            }
        }
        // ---- phi_x layer 2 ----
        float ssum[4];
#pragma unroll
        for (int r = 0; r < 4; ++r) {
            float s = 0.f;
#pragma unroll
            for (int nt = 0; nt < 4; ++nt)
                s += silu(xacc[nt][r] + xb1v[nt]) * xw2v[nt];
            ssum[r] = s;
        }
#pragma unroll
        for (int off = 1; off < 16; off <<= 1)
#pragma unroll
            for (int r = 0; r < 4; ++r) ssum[r] += __shfl_xor(ssum[r], off, 64);
        if (l15 == 0) {
#pragma unroll
            for (int r = 0; r < 4; ++r) wv[q * 4 + r] = ssum[r] + xb2v;
        }

        // ---- segmented per-dst aggregation ----
        int dstv[17];
#pragma unroll
        for (int rr = 0; rr < 16; ++rr) dstv[rr] = __shfl(didx, rr, 64);
        dstv[16] = -1;

        float macc = 0.f;
#pragma unroll
        for (int rr = 0; rr < 16; ++rr) {
            macc += bf2f(act[rr * ROWP + lane]);
            if (dstv[rr + 1] != dstv[rr]) {
                atomicAdd(&m_agg[dstv[rr] * 64 + lane], macc);
                macc = 0.f;
            }
        }
        if (lane < 3) {
            float xac = 0.f;
#pragma unroll
            for (int rr = 0; rr < 16; ++rr) {
                xac += wv[rr] * xd[rr][lane];
                if (dstv[rr + 1] != dstv[rr]) {
                    atomicAdd(&x_agg[dstv[rr] * 3 + lane], xac);
                    xac = 0.f;
                }
            }
        }
    }
}

// -------------------------------------------------------------- node MFMA ---
// R6 config (256,4). h bf16 residual; w2 in registers (single set); zeroes
// m_agg/x_agg after reading (replaces next layer's memsets).
__global__ __launch_bounds__(256, 4) void node_mfma_kernel(
    float* __restrict__ x,
    float* __restrict__ m_agg, float* __restrict__ x_agg,
    const float* __restrict__ w1, const float* __restrict__ b1,   // [128][64]
    const float* __restrict__ w2, const float* __restrict__ b2,   // [64][64]
    unsigned short* __restrict__ h_bf,
    void* __restrict__ outv, const int* __restrict__ flag)
{
    __shared__ unsigned short s_w1p[4 * 4 * 64 * 8];   // 16 KB
    __shared__ unsigned short s_act[4][16 * ROWP];     // 9 KB

    const int tid = threadIdx.x;
    for (int p = tid; p < 4 * 4 * 64 * 8; p += 256) {
        const int j = p & 7, ln = (p >> 3) & 63, nt = (p >> 9) & 3, kc = p >> 11;
        const int k = kc * 32 + (ln >> 4) * 8 + j, n = nt * 16 + (ln & 15);
        s_w1p[p] = f2bf(w1[k * 64 + n]);
    }
    __syncthreads();

    const int bf = flag ? *flag : 1;
    const int lane = tid & 63;
    const int wid = tid >> 6;
    const int l15 = lane & 15;
    const int q = lane >> 4;

    // x update (+ optional out); zero x_agg after read
    for (int n = blockIdx.x * 256 + tid; n < NN; n += gridDim.x * 256) {
#pragma unroll
        for (int c = 0; c < 3; ++c) {
            const float xn = x[n * 4 + c] + x_agg[n * 3 + c];
            x_agg[n * 3 + c] = 0.f;
            x[n * 4 + c] = xn;
            if (outv) {
                if (bf) ((unsigned short*)outv)[NN * HD + n * 3 + c] = f2bf(xn);
                else ((float*)outv)[NN * HD + n * 3 + c] = xn;
            }
        }
    }

    s16x8 bw2[2][4];
#pragma unroll
    for (int kc = 0; kc < 2; ++kc)
#pragma unroll
        for (int nt = 0; nt < 4; ++nt)
#pragma unroll
            for (int j = 0; j < 8; ++j)
                bw2[kc][nt][j] = (short)f2bf(w2[(kc * 32 + q * 8 + j) * 64 + nt * 16 + l15]);

    float b1v[4], b2v[4];
#pragma unroll
    for (int nt = 0; nt < 4; ++nt) {
        b1v[nt] = b1[nt * 16 + l15];
        b2v[nt] = b2[nt * 16 + l15];
    }
    unsigned short* act = s_act[wid];
    const f32x4 zero4 = (f32x4){0.f, 0.f, 0.f, 0.f};

    for (int t = (blockIdx.x << 2) + wid; t < NT_N; t += gridDim.x << 2) {
        const int n = t * 16 + l15;
        const s16x8 a0 = *(const s16x8*)&h_bf[n * 64 + q * 8];
        const s16x8 a1 = *(const s16x8*)&h_bf[n * 64 + 32 + q * 8];
        const f32x4 m0 = *(const f32x4*)&m_agg[n * 64 + q * 8];
        const f32x4 m1 = *(const f32x4*)&m_agg[n * 64 + q * 8 + 4];
        const f32x4 m2 = *(const f32x4*)&m_agg[n * 64 + 32 + q * 8];
        const f32x4 m3 = *(const f32x4*)&m_agg[n * 64 + 32 + q * 8 + 4];
        // zero after read (replaces next layer's memset; disjoint coverage)
        *(f32x4*)&m_agg[n * 64 + q * 8] = zero4;
        *(f32x4*)&m_agg[n * 64 + q * 8 + 4] = zero4;
        *(f32x4*)&m_agg[n * 64 + 32 + q * 8] = zero4;
        *(f32x4*)&m_agg[n * 64 + 32 + q * 8 + 4] = zero4;
        s16x8 a2, a3;
#pragma unroll
        for (int j = 0; j < 4; ++j) {
            a2[j] = (short)f2bf(m0[j]); a2[4 + j] = (short)f2bf(m1[j]);
            a3[j] = (short)f2bf(m2[j]); a3[4 + j] = (short)f2bf(m3[j]);
        }

        f32x4 acc[4];
#pragma unroll
        for (int nt = 0; nt < 4; ++nt) acc[nt] = zero4;
#pragma unroll
        for (int kc = 0; kc < 4; ++kc) {
            const s16x8 a = (kc == 0) ? a0 : (kc == 1) ? a1 : (kc == 2) ? a2 : a3;
#pragma unroll
            for (int nt = 0; nt < 4; ++nt) {
                const s16x8 b = *(const s16x8*)&s_w1p[((kc * 4 + nt) * 64 + lane) * 8];
                acc[nt] = __builtin_amdgcn_mfma_f32_16x16x32_bf16(a, b, acc[nt], 0, 0, 0);
            }
        }
#pragma unroll
        for (int nt = 0; nt < 4; ++nt)
#pragma unroll
            for (int r = 0; r < 4; ++r)
                act[(q * 4 + r) * ROWP + nt * 16 + l15] = f2bf_t(silu(acc[nt][r] + b1v[nt]));

        f32x4 acc2[4];
#pragma unroll
        for (int nt = 0; nt < 4; ++nt) acc2[nt] = zero4;
#pragma unroll
        for (int kc = 0; kc < 2; ++kc) {
            const s16x8 a = *(const s16x8*)&act[l15 * ROWP + kc * 32 + q * 8];
#pragma unroll
            for (int nt = 0; nt < 4; ++nt)
                acc2[nt] = __builtin_amdgcn_mfma_f32_16x16x32_bf16(a, bw2[kc][nt], acc2[nt], 0, 0, 0);
        }
#pragma unroll
        for (int nt = 0; nt < 4; ++nt)
#pragma unroll
            for (int r = 0; r < 4; ++r) {
                const int row = t * 16 + q * 4 + r, col = nt * 16 + l15;
                const float hn = bf2f(h_bf[row * 64 + col]) + acc2[nt][r] + b2v[nt];
                h_bf[row * 64 + col] = f2bf(hn);
                if (outv) {
                    if (bf) ((unsigned short*)outv)[row * 64 + col] = f2bf(hn);
                    else ((float*)outv)[row * 64 + col] = hn;
                }
            }
    }
}

// -------------------------------------------------------------- launch ------
extern "C" void kernel_launch(void* const* d_in, const int* in_sizes, int n_in,
                              void* d_out, int out_size, void* d_ws, size_t ws_size,
                              hipStream_t stream) {
    const int* an = (const int*)d_in[0];
    const void* pos = d_in[1];
    const int* ei = (const int*)d_in[2];

    int wi = 4;
    if (n_in > 4 && in_sizes[4] == 6400) wi = 4;
    else if (n_in > 3 && in_sizes[3] == 6400) wi = 3;
    const void* emb = d_in[wi];
    const void* e_w1 = d_in[wi + 1];
    const void* e_b1 = d_in[wi + 2];
    const void* e_w2 = d_in[wi + 3];
    const void* e_b2 = d_in[wi + 4];
    const void* h_w1 = d_in[wi + 5];
    const void* h_b1 = d_in[wi + 6];
    const void* h_w2 = d_in[wi + 7];
    const void* h_b2 = d_in[wi + 8];
    const void* x_w1 = d_in[wi + 9];
    const void* x_b1 = d_in[wi + 10];
    const void* x_w2 = d_in[wi + 11];
    const void* x_b2 = d_in[wi + 12];

    float* ws = (float*)d_ws;
    int* flag = (int*)(ws + FLAG_OFF);
    float* wbuf = ws + WB_OFF;
    float* x = ws + X_OFF;
    float* m_agg = ws + MAGG_OFF;
    float* x_agg = ws + XAGG_OFF;
    unsigned short* h_bf = (unsigned short*)(ws + HBF_OFF);
    int* cnt = (int*)(ws + CNT_OFF);
    int* csum = (int*)(ws + CSUM_OFF);
    int* incl = (int*)(ws + INCL_OFF);
    int2* pair = (int2*)(ws + PAIR_OFF);

    hipMemsetAsync(cnt, 0, NCH * 256 * sizeof(int), stream);
    prep_kernel<<<784, 256, 0, stream>>>(an, pos, ei, emb,
        e_w1, e_b1, e_w2, e_b2, h_w1, h_b1, h_w2, h_b2,
        x_w1, x_b1, x_w2, x_b2, wbuf, x, h_bf, cnt, flag);
    scan1_kernel<<<NCH, 256, 0, stream>>>(cnt, incl, csum);
    scan2_kernel<<<1, 256, 0, stream>>>(csum);
    scan3_kernel<<<NCH, 256, 0, stream>>>(cnt, incl, csum);
    scatter_kernel<<<512, 256, 0, stream>>>(ei, cnt, pair);

    hipMemsetAsync(m_agg, 0, (size_t)NN * HD * sizeof(float), stream);
    hipMemsetAsync(x_agg, 0, (size_t)NN * 3 * sizeof(float), stream);

    for (int l = 0; l < NL; ++l) {
        edge_mfma_kernel<<<1024, 256, 0, stream>>>(h_bf, x, pair,
            wbuf + EW1_O + l * 129 * 64, wbuf + EB1_O + l * 64,
            wbuf + EB2_O + l * 64,
            wbuf + EW2_O + l * 64 * 64,
            wbuf + XW1_O + l * 64 * 64, wbuf + XB1_O + l * 64,
            wbuf + XW2_O + l * 64, wbuf + XB2_O + l,
            m_agg, x_agg);

        void* out_p = (l == NL - 1) ? d_out : nullptr;
        node_mfma_kernel<<<782, 256, 0, stream>>>(x, m_agg, x_agg,
            wbuf + HW1_O + l * 128 * 64, wbuf + HB1_O + l * 64,
            wbuf + HW2_O + l * 64 * 64, wbuf + HB2_O + l * 64,
            h_bf, out_p, flag);
    }
}

// Round 14
// 441.287 us; speedup vs baseline: 1.1275x; 1.0467x over previous
//
#include <hip/hip_runtime.h>

#define NN 50000
#define NE 800000
#define HD 64
#define NL 2
#define NT_E (NE / 16)   // 50000 edge tiles
#define NT_N (NN / 16)   // 3125 node tiles
#define NCH 196          // scan chunks: 196*256 = 50176 >= NN+1

typedef __attribute__((ext_vector_type(4))) float f32x4;
typedef __attribute__((ext_vector_type(8))) short s16x8;

// ---- d_ws layout (float element offsets) ----
#define FLAG_OFF 0
#define WB_OFF   16
#define EMB_O 0
#define EW1_O 6400
#define EB1_O 22912
#define EW2_O 23040
#define EB2_O 31232
#define HW1_O 31360
#define HB1_O 47744
#define HW2_O 47872
#define HB2_O 56064
#define XW1_O 56192
#define XB1_O 64384
#define XW2_O 64512
#define XB2_O 64640
#define X_OFF    (WB_OFF + 64656)              // fp32 x, padded [NN][4]
#define MAGG_OFF (X_OFF + NN * 4)
#define XAGG_OFF (MAGG_OFF + NN * HD)
#define HBF_OFF  (XAGG_OFF + NN * 3)           // ushort[NN*64]
#define CNT_OFF  (HBF_OFF + NN * 32)
#define CSUM_OFF (CNT_OFF + NCH * 256)
#define INCL_OFF (CSUM_OFF + 256)
#define PAIR_OFF (INCL_OFF + NCH * 256)        // int2[NE]

#define ROWP 72

__device__ __forceinline__ float bf2f(unsigned short u) {
    return __uint_as_float(((unsigned int)u) << 16);
}
__device__ __forceinline__ unsigned short f2bf(float f) {      // RNE
    unsigned int i = __float_as_uint(f);
    i += 0x7fffu + ((i >> 16) & 1u);
    return (unsigned short)(i >> 16);
}
__device__ __forceinline__ unsigned short f2bf_t(float f) {    // trunc (GEMM temps)
    return (unsigned short)(__float_as_uint(f) >> 16);
}
__device__ __forceinline__ float silu(float v) {               // no div sequence
    const float e = __expf(-v);
    return v * __builtin_amdgcn_rcpf(1.0f + e);
}
__device__ __forceinline__ float ldf(const void* p, int i, int bf) {
    return bf ? bf2f(((const unsigned short*)p)[i]) : ((const float*)p)[i];
}
// per-wave bf16-vs-fp32 input detection (all waves agree; no global dep)
__device__ __forceinline__ int detect_bf(const void* pos) {
    const int lane = threadIdx.x & 63;
    const float v = bf2f(((const unsigned short*)pos)[2 * lane]);
    const float a = fabsf(v);
    const unsigned long long m = __ballot(a >= 1e-6f && a <= 1e6f);
    return (__popcll(m) >= 32) ? 1 : 0;
}

// -------------------------------------------------------------- prep --------
// Fused: detect + convert(x, weights) + init_h + hist. cnt must be pre-zeroed.
__global__ __launch_bounds__(256) void prep_kernel(
    const int* __restrict__ an, const void* pos, const int* __restrict__ ei,
    const void* emb,
    const void* ew1, const void* eb1, const void* ew2, const void* eb2,
    const void* hw1, const void* hb1, const void* hw2, const void* hb2,
    const void* xw1, const void* xb1, const void* xw2, const void* xb2,
    float* __restrict__ wbuf, float* __restrict__ x,
    unsigned short* __restrict__ h_bf, int* __restrict__ cnt,
    int* __restrict__ flag)
{
    const int bf = detect_bf(pos);
    const int tid = blockIdx.x * blockDim.x + threadIdx.x;
    if (tid == 0) *flag = bf;
    const int stride = gridDim.x * blockDim.x;

    for (int n = tid; n < NN; n += stride) {
        x[n * 4 + 0] = ldf(pos, n * 3 + 0, bf);
        x[n * 4 + 1] = ldf(pos, n * 3 + 1, bf);
        x[n * 4 + 2] = ldf(pos, n * 3 + 2, bf);
        x[n * 4 + 3] = 0.f;
    }
    for (int i = tid; i < 16512; i += stride) wbuf[EW1_O + i] = ldf(ew1, i, bf);
    for (int i = tid; i < 128; i += stride) wbuf[EB1_O + i] = ldf(eb1, i, bf);
    for (int i = tid; i < 8192; i += stride) wbuf[EW2_O + i] = ldf(ew2, i, bf);
    for (int i = tid; i < 128; i += stride) wbuf[EB2_O + i] = ldf(eb2, i, bf);
    for (int i = tid; i < 16384; i += stride) wbuf[HW1_O + i] = ldf(hw1, i, bf);
    for (int i = tid; i < 128; i += stride) wbuf[HB1_O + i] = ldf(hb1, i, bf);
    for (int i = tid; i < 8192; i += stride) wbuf[HW2_O + i] = ldf(hw2, i, bf);
    for (int i = tid; i < 128; i += stride) wbuf[HB2_O + i] = ldf(hb2, i, bf);
    for (int i = tid; i < 8192; i += stride) wbuf[XW1_O + i] = ldf(xw1, i, bf);
    for (int i = tid; i < 128; i += stride) wbuf[XB1_O + i] = ldf(xb1, i, bf);
    for (int i = tid; i < 128; i += stride) wbuf[XW2_O + i] = ldf(xw2, i, bf);
    for (int i = tid; i < 2; i += stride) wbuf[XB2_O + i] = ldf(xb2, i, bf);

    // init h_bf directly from raw emb
    for (int i = tid; i < NN * HD; i += stride) {
        int a = an[i >> 6];
        a = (a < 0) ? 0 : (a > 99 ? 99 : a);
        h_bf[i] = f2bf(ldf(emb, a * HD + (i & 63), bf));
    }
    // histogram of dst
    for (int e = tid; e < NE; e += stride) {
        int d = ei[NE + e];
        d = (d < 0) ? 0 : (d >= NN ? NN - 1 : d);
        atomicAdd(&cnt[d], 1);
    }
}

// -------------------------------------------------------------- sort --------
__global__ __launch_bounds__(256) void scan1_kernel(
    const int* __restrict__ cnt, int* __restrict__ incl, int* __restrict__ csum)
{
    __shared__ int s[256];
    const int t = threadIdx.x, b = blockIdx.x, i = b * 256 + t;
    s[t] = cnt[i];
    __syncthreads();
#pragma unroll
    for (int o = 1; o < 256; o <<= 1) {
        const int u = (t >= o) ? s[t - o] : 0;
        __syncthreads();
        s[t] += u;
        __syncthreads();
    }
    incl[i] = s[t];
    if (t == 255) csum[b] = s[255];
}

// scan2 folded in: every block prefix-sums the 196 chunk totals in LDS.
__global__ __launch_bounds__(256) void scan3_kernel(
    int* __restrict__ cnt, const int* __restrict__ incl, const int* __restrict__ csum)
{
    __shared__ int s[256];
    const int t = threadIdx.x, b = blockIdx.x;
    s[t] = (t < NCH) ? csum[t] : 0;
    __syncthreads();
#pragma unroll
    for (int o = 1; o < 256; o <<= 1) {
        const int u = (t >= o) ? s[t - o] : 0;
        __syncthreads();
        s[t] += u;
        __syncthreads();
    }
    const int off = (b > 0) ? s[b - 1] : 0;
    const int i = b * 256 + t;
    cnt[i] = incl[i] + off - cnt[i];
}

__global__ __launch_bounds__(256) void scatter_kernel(
    const int* __restrict__ ei, int* __restrict__ cur, int2* __restrict__ pair)
{
    const int stride = gridDim.x * blockDim.x;
    for (int e = blockIdx.x * blockDim.x + threadIdx.x; e < NE; e += stride) {
        int s = ei[e];
        int d = ei[NE + e];
        s = (s < 0) ? 0 : (s >= NN ? NN - 1 : s);
        d = (d < 0) ? 0 : (d >= NN ? NN - 1 : d);
        const int p = atomicAdd(&cur[d], 1);
        pair[p] = make_int2(s, d);
    }
}

// -------------------------------------------------------------- edge MFMA ---
// PROVEN R6 CONFIG (256,4; one reg frag set; xw1 in LDS; RNE m) + CONTIGUOUS
// per-wave tile ranges: each wave owns ~12 consecutive dst-sorted tiles, so
// dst-side gathers/atomics hit a ~50 KB window (L2-local) instead of the
// whole array. Do NOT tighten VGPR cap or add a 2nd frag set (spills:R7/8/10).
__global__ __launch_bounds__(256, 4) void edge_mfma_kernel(
    const unsigned short* __restrict__ h_bf, const float* __restrict__ x,
    const int2* __restrict__ pair,
    const float* __restrict__ w1, const float* __restrict__ b1,
    const float* __restrict__ b2,
    const float* __restrict__ w2,
    const float* __restrict__ xw1, const float* __restrict__ xb1,
    const float* __restrict__ xw2, const float* __restrict__ xb2,
    float* __restrict__ m_agg, float* __restrict__ x_agg)
{
    __shared__ unsigned short s_w1p[4 * 4 * 64 * 8];   // 16 KB
    __shared__ unsigned short s_xw1p[2 * 4 * 64 * 8];  // 8 KB
    __shared__ unsigned short s_act[4][16 * ROWP];     // 9 KB
    __shared__ float s_xd[4][16][4];                   // 1 KB
    __shared__ float s_wv[4][16];                      // 256 B

    const int tid = threadIdx.x;
    for (int p = tid; p < 4 * 4 * 64 * 8; p += 256) {
        const int j = p & 7, ln = (p >> 3) & 63, nt = (p >> 9) & 3, kc = p >> 11;
        const int k = kc * 32 + (ln >> 4) * 8 + j, n = nt * 16 + (ln & 15);
        s_w1p[p] = f2bf(w1[k * 64 + n]);
    }
    for (int p = tid; p < 2 * 4 * 64 * 8; p += 256) {
        const int j = p & 7, ln = (p >> 3) & 63, nt = (p >> 9) & 3, kc = p >> 11;
        const int k = kc * 32 + (ln >> 4) * 8 + j, n = nt * 16 + (ln & 15);
        s_xw1p[p] = f2bf(xw1[k * 64 + n]);
    }
    __syncthreads();

    const int lane = tid & 63;
    const int wid = tid >> 6;
    const int l15 = lane & 15;
    const int q = lane >> 4;

    // single register-held B-frag set (phi_e L2) — one set is spill-free
    s16x8 bw2[2][4];
#pragma unroll
    for (int kc = 0; kc < 2; ++kc)
#pragma unroll
        for (int nt = 0; nt < 4; ++nt)
#pragma unroll
            for (int j = 0; j < 8; ++j)
                bw2[kc][nt][j] = (short)f2bf(w2[(kc * 32 + q * 8 + j) * 64 + nt * 16 + l15]);

    float b1v[4], b2v[4], xb1v[4], xw2v[4], wrv[4];
#pragma unroll
    for (int nt = 0; nt < 4; ++nt) {
        b1v[nt] = b1[nt * 16 + l15];
        b2v[nt] = b2[nt * 16 + l15];
        xb1v[nt] = xb1[nt * 16 + l15];
        xw2v[nt] = xw2[nt * 16 + l15];
        wrv[nt] = w1[128 * 64 + nt * 16 + l15];
    }
    const float xb2v = xb2[0];

    unsigned short* act = s_act[wid];
    float (*xd)[4] = s_xd[wid];
    float* wv = s_wv[wid];

    // balanced contiguous partition of tiles over waves
    const int gwave = (blockIdx.x << 2) + wid;
    const int nwaves = gridDim.x << 2;
    const int qlo = NT_E / nwaves;
    const int rem = NT_E - qlo * nwaves;
    const int tbeg = gwave * qlo + (gwave < rem ? gwave : rem);
    const int tend = tbeg + qlo + (gwave < rem ? 1 : 0);

    for (int t = tbeg; t < tend; ++t) {
        const int e0 = t * 16;
        const int2 e = pair[e0 + l15];
        const int sidx = e.x, didx = e.y;
        const f32x4 xs = *(const f32x4*)&x[sidx * 4];
        const f32x4 xdv = *(const f32x4*)&x[didx * 4];
        const float ax = xs[0] - xdv[0];
        const float ay = xs[1] - xdv[1];
        const float az = xs[2] - xdv[2];
        const float rme = sqrtf(ax * ax + ay * ay + az * az);
        if (lane < 16) { xd[lane][0] = ax; xd[lane][1] = ay; xd[lane][2] = az; }

        const s16x8 a_hd0 = *(const s16x8*)&h_bf[didx * 64 + q * 8];
        const s16x8 a_hd1 = *(const s16x8*)&h_bf[didx * 64 + 32 + q * 8];
        const s16x8 a_hs0 = *(const s16x8*)&h_bf[sidx * 64 + q * 8];
        const s16x8 a_hs1 = *(const s16x8*)&h_bf[sidx * 64 + 32 + q * 8];

        // ---- phi_e layer 1 ----
        f32x4 acc[4];
#pragma unroll
        for (int nt = 0; nt < 4; ++nt) acc[nt] = (f32x4){0.f, 0.f, 0.f, 0.f};
#pragma unroll
        for (int kc = 0; kc < 4; ++kc) {
            const s16x8 a = (kc == 0) ? a_hd0 : (kc == 1) ? a_hd1 : (kc == 2) ? a_hs0 : a_hs1;
#pragma unroll
            for (int nt = 0; nt < 4; ++nt) {
                const s16x8 b = *(const s16x8*)&s_w1p[((kc * 4 + nt) * 64 + lane) * 8];
                acc[nt] = __builtin_amdgcn_mfma_f32_16x16x32_bf16(a, b, acc[nt], 0, 0, 0);
            }
        }
        float rv[4];
#pragma unroll
        for (int r = 0; r < 4; ++r) rv[r] = __shfl(rme, q * 4 + r, 64);
#pragma unroll
        for (int nt = 0; nt < 4; ++nt)
#pragma unroll
            for (int r = 0; r < 4; ++r) {
                const float v = silu(acc[nt][r] + b1v[nt] + rv[r] * wrv[nt]);
                act[(q * 4 + r) * ROWP + nt * 16 + l15] = f2bf_t(v);
            }

        // ---- phi_e layer 2 (B in registers) -> m (RNE: feeds 16-deep sums) -
        f32x4 acc2[4];
#pragma unroll
        for (int nt = 0; nt < 4; ++nt) acc2[nt] = (f32x4){0.f, 0.f, 0.f, 0.f};
#pragma unroll
        for (int kc = 0; kc < 2; ++kc) {
            const s16x8 a = *(const s16x8*)&act[l15 * ROWP + kc * 32 + q * 8];
#pragma unroll
            for (int nt = 0; nt < 4; ++nt)
                acc2[nt] = __builtin_amdgcn_mfma_f32_16x16x32_bf16(a, bw2[kc][nt], acc2[nt], 0, 0, 0);
        }
#pragma unroll
        for (int nt = 0; nt < 4; ++nt)
#pragma unroll
            for (int r = 0; r < 4; ++r) {
                const float v = silu(acc2[nt][r] + b2v[nt]);
                act[(q * 4 + r) * ROWP + nt * 16 + l15] = f2bf(v);
            }

        // ---- phi_x layer 1 (B from LDS) ----
        f32x4 xacc[4];
#pragma unroll
        for (int nt = 0; nt < 4; ++nt) xacc[nt] = (f32x4){0.f, 0.f, 0.f, 0.f};
#pragma unroll
        for (int kc = 0; kc < 2; ++kc) {
            const s16x8 a = *(const s16x8*)&act[l15 * ROWP + kc * 32 + q * 8];
#pragma unroll
            for (int nt = 0; nt < 4; ++nt) {
                const s16x8 b = *(const s16x8*)&s_xw1p[((kc * 4 + nt) * 64 + lane) * 8];
                xacc[nt] = __builtin_amdgcn_mfma_f32_16x16x32_bf16(a, b, xacc[nt], 0, 0, 0);
            }
        }
        // ---- phi_x layer 2 ----
        float ssum[4];
#pragma unroll
        for (int r = 0; r < 4; ++r) {
            float s = 0.f;
#pragma unroll
            for (int nt = 0; nt < 4; ++nt)
                s += silu(xacc[nt][r] + xb1v[nt]) * xw2v[nt];
            ssum[r] = s;
        }
#pragma unroll
        for (int off = 1; off < 16; off <<= 1)
#pragma unroll
            for (int r = 0; r < 4; ++r) ssum[r] += __shfl_xor(ssum[r], off, 64);
        if (l15 == 0) {
#pragma unroll
            for (int r = 0; r < 4; ++r) wv[q * 4 + r] = ssum[r] + xb2v;
        }

        // ---- segmented per-dst aggregation ----
        int dstv[17];
#pragma unroll
        for (int rr = 0; rr < 16; ++rr) dstv[rr] = __shfl(didx, rr, 64);
        dstv[16] = -1;

        float macc = 0.f;
#pragma unroll
        for (int rr = 0; rr < 16; ++rr) {
            macc += bf2f(act[rr * ROWP + lane]);
            if (dstv[rr + 1] != dstv[rr]) {
                atomicAdd(&m_agg[dstv[rr] * 64 + lane], macc);
                macc = 0.f;
            }
        }
        if (lane < 3) {
            float xac = 0.f;
#pragma unroll
            for (int rr = 0; rr < 16; ++rr) {
                xac += wv[rr] * xd[rr][lane];
                if (dstv[rr + 1] != dstv[rr]) {
                    atomicAdd(&x_agg[dstv[rr] * 3 + lane], xac);
                    xac = 0.f;
                }
            }
        }
    }
}

// -------------------------------------------------------------- node MFMA ---
// R6 config (256,4). h bf16 residual; w2 in registers (single set); zeroes
// m_agg/x_agg after reading. Contiguous per-wave tiles.
__global__ __launch_bounds__(256, 4) void node_mfma_kernel(
    float* __restrict__ x,
    float* __restrict__ m_agg, float* __restrict__ x_agg,
    const float* __restrict__ w1, const float* __restrict__ b1,   // [128][64]
    const float* __restrict__ w2, const float* __restrict__ b2,   // [64][64]
    unsigned short* __restrict__ h_bf,
    void* __restrict__ outv, const int* __restrict__ flag)
{
    __shared__ unsigned short s_w1p[4 * 4 * 64 * 8];   // 16 KB
    __shared__ unsigned short s_act[4][16 * ROWP];     // 9 KB

    const int tid = threadIdx.x;
    for (int p = tid; p < 4 * 4 * 64 * 8; p += 256) {
        const int j = p & 7, ln = (p >> 3) & 63, nt = (p >> 9) & 3, kc = p >> 11;
        const int k = kc * 32 + (ln >> 4) * 8 + j, n = nt * 16 + (ln & 15);
        s_w1p[p] = f2bf(w1[k * 64 + n]);
    }
    __syncthreads();

    const int bf = flag ? *flag : 1;
    const int lane = tid & 63;
    const int wid = tid >> 6;
    const int l15 = lane & 15;
    const int q = lane >> 4;

    // x update (+ optional out); zero x_agg after read
    for (int n = blockIdx.x * 256 + tid; n < NN; n += gridDim.x * 256) {
#pragma unroll
        for (int c = 0; c < 3; ++c) {
            const float xn = x[n * 4 + c] + x_agg[n * 3 + c];
            x_agg[n * 3 + c] = 0.f;
            x[n * 4 + c] = xn;
            if (outv) {
                if (bf) ((unsigned short*)outv)[NN * HD + n * 3 + c] = f2bf(xn);
                else ((float*)outv)[NN * HD + n * 3 + c] = xn;
            }
        }
    }

    s16x8 bw2[2][4];
#pragma unroll
    for (int kc = 0; kc < 2; ++kc)
#pragma unroll
        for (int nt = 0; nt < 4; ++nt)
#pragma unroll
            for (int j = 0; j < 8; ++j)
                bw2[kc][nt][j] = (short)f2bf(w2[(kc * 32 + q * 8 + j) * 64 + nt * 16 + l15]);

    float b1v[4], b2v[4];
#pragma unroll
    for (int nt = 0; nt < 4; ++nt) {
        b1v[nt] = b1[nt * 16 + l15];
        b2v[nt] = b2[nt * 16 + l15];
    }
    unsigned short* act = s_act[wid];
    const f32x4 zero4 = (f32x4){0.f, 0.f, 0.f, 0.f};

    // balanced contiguous partition of node tiles over waves
    const int gwave = (blockIdx.x << 2) + wid;
    const int nwaves = gridDim.x << 2;
    const int qlo = NT_N / nwaves;
    const int rem = NT_N - qlo * nwaves;
    const int tbeg = gwave * qlo + (gwave < rem ? gwave : rem);
    const int tend = tbeg + qlo + (gwave < rem ? 1 : 0);

    for (int t = tbeg; t < tend; ++t) {
        const int n = t * 16 + l15;
        const s16x8 a0 = *(const s16x8*)&h_bf[n * 64 + q * 8];
        const s16x8 a1 = *(const s16x8*)&h_bf[n * 64 + 32 + q * 8];
        const f32x4 m0 = *(const f32x4*)&m_agg[n * 64 + q * 8];
        const f32x4 m1 = *(const f32x4*)&m_agg[n * 64 + q * 8 + 4];
        const f32x4 m2 = *(const f32x4*)&m_agg[n * 64 + 32 + q * 8];
        const f32x4 m3 = *(const f32x4*)&m_agg[n * 64 + 32 + q * 8 + 4];
        // zero after read (replaces next layer's memset; disjoint coverage)
        *(f32x4*)&m_agg[n * 64 + q * 8] = zero4;
        *(f32x4*)&m_agg[n * 64 + q * 8 + 4] = zero4;
        *(f32x4*)&m_agg[n * 64 + 32 + q * 8] = zero4;
        *(f32x4*)&m_agg[n * 64 + 32 + q * 8 + 4] = zero4;
        s16x8 a2, a3;
#pragma unroll
        for (int j = 0; j < 4; ++j) {
            a2[j] = (short)f2bf(m0[j]); a2[4 + j] = (short)f2bf(m1[j]);
            a3[j] = (short)f2bf(m2[j]); a3[4 + j] = (short)f2bf(m3[j]);
        }

        f32x4 acc[4];
#pragma unroll
        for (int nt = 0; nt < 4; ++nt) acc[nt] = zero4;
#pragma unroll
        for (int kc = 0; kc < 4; ++kc) {
            const s16x8 a = (kc == 0) ? a0 : (kc == 1) ? a1 : (kc == 2) ? a2 : a3;
#pragma unroll
            for (int nt = 0; nt < 4; ++nt) {
                const s16x8 b = *(const s16x8*)&s_w1p[((kc * 4 + nt) * 64 + lane) * 8];
                acc[nt] = __builtin_amdgcn_mfma_f32_16x16x32_bf16(a, b, acc[nt], 0, 0, 0);
            }
        }
#pragma unroll
        for (int nt = 0; nt < 4; ++nt)
#pragma unroll
            for (int r = 0; r < 4; ++r)
                act[(q * 4 + r) * ROWP + nt * 16 + l15] = f2bf_t(silu(acc[nt][r] + b1v[nt]));

        f32x4 acc2[4];
#pragma unroll
        for (int nt = 0; nt < 4; ++nt) acc2[nt] = zero4;
#pragma unroll
        for (int kc = 0; kc < 2; ++kc) {
            const s16x8 a = *(const s16x8*)&act[l15 * ROWP + kc * 32 + q * 8];
#pragma unroll
            for (int nt = 0; nt < 4; ++nt)
                acc2[nt] = __builtin_amdgcn_mfma_f32_16x16x32_bf16(a, bw2[kc][nt], acc2[nt], 0, 0, 0);
        }
#pragma unroll
        for (int nt = 0; nt < 4; ++nt)
#pragma unroll
            for (int r = 0; r < 4; ++r) {
                const int row = t * 16 + q * 4 + r, col = nt * 16 + l15;
                const float hn = bf2f(h_bf[row * 64 + col]) + acc2[nt][r] + b2v[nt];
                h_bf[row * 64 + col] = f2bf(hn);
                if (outv) {
                    if (bf) ((unsigned short*)outv)[row * 64 + col] = f2bf(hn);
                    else ((float*)outv)[row * 64 + col] = hn;
                }
            }
    }
}

// -------------------------------------------------------------- launch ------
extern "C" void kernel_launch(void* const* d_in, const int* in_sizes, int n_in,
                              void* d_out, int out_size, void* d_ws, size_t ws_size,
                              hipStream_t stream) {
    const int* an = (const int*)d_in[0];
    const void* pos = d_in[1];
    const int* ei = (const int*)d_in[2];

    int wi = 4;
    if (n_in > 4 && in_sizes[4] == 6400) wi = 4;
    else if (n_in > 3 && in_sizes[3] == 6400) wi = 3;
    const void* emb = d_in[wi];
    const void* e_w1 = d_in[wi + 1];
    const void* e_b1 = d_in[wi + 2];
    const void* e_w2 = d_in[wi + 3];
    const void* e_b2 = d_in[wi + 4];
    const void* h_w1 = d_in[wi + 5];
    const void* h_b1 = d_in[wi + 6];
    const void* h_w2 = d_in[wi + 7];
    const void* h_b2 = d_in[wi + 8];
    const void* x_w1 = d_in[wi + 9];
    const void* x_b1 = d_in[wi + 10];
    const void* x_w2 = d_in[wi + 11];
    const void* x_b2 = d_in[wi + 12];

    float* ws = (float*)d_ws;
    int* flag = (int*)(ws + FLAG_OFF);
    float* wbuf = ws + WB_OFF;
    float* x = ws + X_OFF;
    float* m_agg = ws + MAGG_OFF;
    float* x_agg = ws + XAGG_OFF;
    unsigned short* h_bf = (unsigned short*)(ws + HBF_OFF);
    int* cnt = (int*)(ws + CNT_OFF);
    int* csum = (int*)(ws + CSUM_OFF);
    int* incl = (int*)(ws + INCL_OFF);
    int2* pair = (int2*)(ws + PAIR_OFF);

    hipMemsetAsync(cnt, 0, NCH * 256 * sizeof(int), stream);
    prep_kernel<<<784, 256, 0, stream>>>(an, pos, ei, emb,
        e_w1, e_b1, e_w2, e_b2, h_w1, h_b1, h_w2, h_b2,
        x_w1, x_b1, x_w2, x_b2, wbuf, x, h_bf, cnt, flag);
    scan1_kernel<<<NCH, 256, 0, stream>>>(cnt, incl, csum);
    scan3_kernel<<<NCH, 256, 0, stream>>>(cnt, incl, csum);
    scatter_kernel<<<512, 256, 0, stream>>>(ei, cnt, pair);

    hipMemsetAsync(m_agg, 0, (size_t)NN * HD * sizeof(float), stream);
    hipMemsetAsync(x_agg, 0, (size_t)NN * 3 * sizeof(float), stream);

    for (int l = 0; l < NL; ++l) {
        edge_mfma_kernel<<<1024, 256, 0, stream>>>(h_bf, x, pair,
            wbuf + EW1_O + l * 129 * 64, wbuf + EB1_O + l * 64,
            wbuf + EB2_O + l * 64,
            wbuf + EW2_O + l * 64 * 64,
            wbuf + XW1_O + l * 64 * 64, wbuf + XB1_O + l * 64,
            wbuf + XW2_O + l * 64, wbuf + XB2_O + l,
            m_agg, x_agg);

        void* out_p = (l == NL - 1) ? d_out : nullptr;
        node_mfma_kernel<<<782, 256, 0, stream>>>(x, m_agg, x_agg,
            wbuf + HW1_O + l * 128 * 64, wbuf + HB1_O + l * 64,
            wbuf + HW2_O + l * 64 * 64, wbuf + HB2_O + l * 64,
            h_bf, out_p, flag);
    }
}